// Round 13
// baseline (150.655 us; speedup 1.0000x reference)
//
#include <hip/hip_runtime.h>

#define NROWS 100000
#define IN_DIM 512
#define NTILES 6250          // 16-row tiles, 6250*16 = 100000 exact

typedef __attribute__((ext_vector_type(8))) short short8;
typedef __attribute__((ext_vector_type(4))) float f32x4;
typedef unsigned int u32;
typedef const __attribute__((address_space(1))) u32* gptr_t;
typedef __attribute__((address_space(3))) u32* lptr_t;

__device__ inline unsigned short f2bf(float f) {
    union { float f; unsigned u; } v; v.f = f;
    unsigned u = v.u;
    return (unsigned short)((u + 0x7FFFu + ((u >> 16) & 1u)) >> 16);
}

// Prepack: B-fragments (bf16) in exact MFMA lane order + fused que bias.
// B = [80 cols x 512 k]: cols 0..63 = Wv, 64..71 = Wq@Wk, 72..79 = 0.
// Bp layout: [t(5)][ks(16)][lane(64)][e(8)] bf16. Also zeroes the tile counter.
__global__ void qg_prepack(const float* __restrict__ Wk, const float* __restrict__ bk,
                           const float* __restrict__ Wq, const float* __restrict__ bq,
                           const float* __restrict__ Wv,
                           unsigned short* __restrict__ Bp, float* __restrict__ qb,
                           u32* __restrict__ ctr) {
    int id = blockIdx.x * 256 + threadIdx.x;  // 0..5119
    if (id < 8) {
        float s = bq[id];
        #pragma unroll 4
        for (int j = 0; j < 100; ++j) s += Wq[id * 100 + j] * bk[j];
        qb[id] = s;
    }
    if (id == 8) *ctr = 0u;
    if (id >= 5120) return;
    int lane = id & 63;
    int ks = (id >> 6) & 15;
    int t = id >> 10;
    int c = t * 16 + (lane & 15);
    int kk = ks * 32 + (lane >> 4) * 8;
    short8 pk;
    #pragma unroll
    for (int e = 0; e < 8; ++e) {
        int k2 = kk + e;
        float w;
        if (c < 64) {
            w = Wv[c * IN_DIM + k2];
        } else if (c < 72) {
            float s = 0.f;
            #pragma unroll 4
            for (int j = 0; j < 100; ++j) s += Wq[(c - 64) * 100 + j] * Wk[j * IN_DIM + k2];
            w = s;
        } else {
            w = 0.f;
        }
        pk[e] = (short)f2bf(w);
    }
    ((short8*)Bp)[id] = pk;
}

// Main: PERSISTENT, 256 blocks x 256 thr (4 waves), 1 block/CU (142 KB LDS).
// Each wave = independent worker claiming 16-row tiles via atomic counter.
// B resident in LDS (loaded once/block). A streams through a per-wave 5-chunk
// LDS ring fed by global_load_lds (zero VGPR dests -> regalloc-proof depth),
// counted in-order vmcnt ladder; ring spans tile boundaries so next-tile reads
// overlap the epilogue's NT stores.
__global__ __launch_bounds__(256, 1) void qg_main(const float* __restrict__ x,
                                                  const float* __restrict__ bv,
                                                  const unsigned short* __restrict__ Bp,
                                                  const float* __restrict__ qb,
                                                  u32* __restrict__ ctr,
                                                  float* __restrict__ out) {
    __shared__ float Bls[20480];        // 80 KB B fragments (block-shared)
    __shared__ float ring[4][2560];     // per-wave 5-chunk A ring (10 KB each)
    __shared__ float epi[4][1216];      // per-wave epilogue: [16][68] val + [16][8] w
    const int tid = threadIdx.x;
    const int w = tid >> 6;
    const int lane = tid & 63;
    const int g = lane >> 4;            // k sub-block
    const int cl = lane & 15;           // row-within-tile / col-within-tile

    // Bias preload, settled before the hand-counted VMEM region.
    float bvr[4];
    #pragma unroll
    for (int t = 0; t < 4; ++t) bvr[t] = bv[t * 16 + cl];
    float qbr = qb[cl & 7];
    asm volatile("s_waitcnt vmcnt(0)" ::: "memory");

    // Claim first two tiles for this wave.
    int t0 = 0, t1 = 0;
    if (lane == 0) { t0 = (int)atomicAdd(ctr, 1u); t1 = (int)atomicAdd(ctr, 1u); }
    int cur = __shfl(t0, 0);
    int nxt = __shfl(t1, 0);

    // ---- B preload: this wave loads bytes [w*20KB, +20KB) (20 x 1KB) ----
    #pragma unroll
    for (int j = 0; j < 20; ++j) {
        int s16 = w * 1280 + j * 64;    // uniform 16B-slot base
        __builtin_amdgcn_global_load_lds(
            (gptr_t)(const void*)((const char*)Bp + ((size_t)s16 + lane) * 16),
            (lptr_t)(void*)(Bls + (size_t)s16 * 4), 16, 0, 0);
    }

    // Chunk issue: chunk = K-step st of tile rowbase rb -> ring slot (2 x 1KB).
    auto issue_chunk = [&](int rb, int st, int slot) {
        #pragma unroll
        for (int l = 0; l < 2; ++l) {
            int S16 = l * 64 + lane;            // 16B-slot within chunk
            int row = S16 >> 3;
            int c = (S16 & 7) ^ (row & 7);      // XOR bank swizzle (128B-local)
            const float* src = x + (size_t)(rb + row) * IN_DIM + st * 32 + c * 4;
            __builtin_amdgcn_global_load_lds((gptr_t)(const void*)src,
                (lptr_t)(void*)(ring[w] + slot * 512 + l * 256), 16, 0, 0);
        }
    };

    // ---- A prologue: chunks 0..4 of first tile ----
    {
        const int rb0 = cur * 16;
        #pragma unroll
        for (int s = 0; s < 5; ++s) issue_chunk(rb0, s, s);
    }
    asm volatile("s_waitcnt vmcnt(10)" ::: "memory");   // all B done (A may fly)
    __builtin_amdgcn_s_barrier();                        // B visible to all waves

    const short8* b8 = (const short8*)Bls;
    int r0 = 0;                                          // ring phase (local tile ordinal % 5)

// Consume step S of tile cur (ladder literal NW), then refill the freed slot
// with chunk S+5 (same tile for S<=10, next tile for S>=11, guarded by DI).
#define CSTEP(S, NW, RBI, STI, DI) do {                                        \
    asm volatile("s_waitcnt vmcnt(" NW ")" ::: "memory");                      \
    __builtin_amdgcn_sched_barrier(0);                                         \
    {                                                                          \
        const int slot_ = (r0 + (S)) % 5;                                      \
        const float4* a4_ = (const float4*)(ring[w] + slot_ * 512);            \
        float4 f0_ = a4_[cl * 8 + ((g * 2) ^ (cl & 7))];                       \
        float4 f1_ = a4_[cl * 8 + ((g * 2 + 1) ^ (cl & 7))];                   \
        short8 af_;                                                            \
        af_[0] = (short)f2bf(f0_.x); af_[1] = (short)f2bf(f0_.y);              \
        af_[2] = (short)f2bf(f0_.z); af_[3] = (short)f2bf(f0_.w);              \
        af_[4] = (short)f2bf(f1_.x); af_[5] = (short)f2bf(f1_.y);              \
        af_[6] = (short)f2bf(f1_.z); af_[7] = (short)f2bf(f1_.w);              \
        acc[0] = __builtin_amdgcn_mfma_f32_16x16x32_bf16(af_, b8[(0 * 16 + (S)) * 64 + lane], acc[0], 0, 0, 0); \
        acc[1] = __builtin_amdgcn_mfma_f32_16x16x32_bf16(af_, b8[(1 * 16 + (S)) * 64 + lane], acc[1], 0, 0, 0); \
        acc[2] = __builtin_amdgcn_mfma_f32_16x16x32_bf16(af_, b8[(2 * 16 + (S)) * 64 + lane], acc[2], 0, 0, 0); \
        acc[3] = __builtin_amdgcn_mfma_f32_16x16x32_bf16(af_, b8[(3 * 16 + (S)) * 64 + lane], acc[3], 0, 0, 0); \
        acc[4] = __builtin_amdgcn_mfma_f32_16x16x32_bf16(af_, b8[(4 * 16 + (S)) * 64 + lane], acc[4], 0, 0, 0); \
        asm volatile("s_waitcnt lgkmcnt(0)" ::: "memory");                     \
        __builtin_amdgcn_sched_barrier(0);                                     \
        if (DI) issue_chunk((RBI), (STI), slot_);                              \
    }                                                                          \
} while (0)

// One 16-step tile. L04 = vmcnt literal for steps 0..4 ("8" on a wave's first
// tile, "40" after: lets the previous tile's 32 NT stores ride in the FIFO).
#define TILE16(L04) do {                                                       \
    const int rbc_ = cur * 16;                                                 \
    const int rbn_ = nxt * 16;                                                 \
    const bool hn_ = (nxt < NTILES);                                           \
    CSTEP(0,  L04, rbc_, 5,  true);                                            \
    CSTEP(1,  L04, rbc_, 6,  true);                                            \
    CSTEP(2,  L04, rbc_, 7,  true);                                            \
    CSTEP(3,  L04, rbc_, 8,  true);                                            \
    CSTEP(4,  L04, rbc_, 9,  true);                                            \
    CSTEP(5,  "8", rbc_, 10, true);                                            \
    CSTEP(6,  "8", rbc_, 11, true);                                            \
    CSTEP(7,  "8", rbc_, 12, true);                                            \
    CSTEP(8,  "8", rbc_, 13, true);                                            \
    CSTEP(9,  "8", rbc_, 14, true);                                            \
    CSTEP(10, "8", rbc_, 15, true);                                            \
    CSTEP(11, "8", rbn_, 0,  hn_);                                             \
    CSTEP(12, "8", rbn_, 1,  hn_);                                             \
    CSTEP(13, "8", rbn_, 2,  hn_);                                             \
    CSTEP(14, "8", rbn_, 3,  hn_);                                             \
    CSTEP(15, "8", rbn_, 4,  hn_);                                             \
} while (0)

    float* vld = epi[w];                 // [16][68]
    float* wld = epi[w] + 16 * 68;       // [16][8]

    bool first = true;
    while (cur < NTILES) {
        // Claim the tile after nxt (result needed only next iteration).
        int ta = 0;
        if (lane == 0) ta = (int)atomicAdd(ctr, 1u);
        int aft = __shfl(ta, 0);

        f32x4 acc[5];
        #pragma unroll
        for (int t = 0; t < 5; ++t) acc[t] = (f32x4){0.f, 0.f, 0.f, 0.f};

        if (first) { TILE16("8"); } else { TILE16("40"); }

        // ---- Epilogue for tile cur (per-wave lockstep; lgkm ordering only) ---
        // C layout: col = lane&15, row = (lane>>4)*4 + reg (verified m89).
        const int rb = cur * 16;
        #pragma unroll
        for (int t = 0; t < 4; ++t) {
            #pragma unroll
            for (int r = 0; r < 4; ++r)
                vld[(g * 4 + r) * 68 + t * 16 + cl] = acc[t][r] + bvr[t];
        }
        if (cl < 8) {
            #pragma unroll
            for (int r = 0; r < 4; ++r)
                wld[(g * 4 + r) * 8 + cl] = acc[4][r] + qbr;
        }
        asm volatile("s_waitcnt lgkmcnt(0)" ::: "memory");

        if (lane < 16) {
            float q[8];
            float m = -1e30f;
            #pragma unroll
            for (int k = 0; k < 8; ++k) { q[k] = wld[lane * 8 + k]; m = fmaxf(m, q[k]); }
            float ssum = 0.f;
            #pragma unroll
            for (int k = 0; k < 8; ++k) { q[k] = __expf(q[k] - m); ssum += q[k]; }
            float inv = 1.f / ssum;
            #pragma unroll
            for (int k = 0; k < 8; ++k) wld[lane * 8 + k] = q[k] * inv;
        }
        asm volatile("s_waitcnt lgkmcnt(0)" ::: "memory");

        // Coalesced NT output: out[row][k][v] = w[k] * val[v]; 1 KB/instr.
        f32x4* outp = (f32x4*)out + (size_t)rb * 128;
        #pragma unroll
        for (int it = 0; it < 32; ++it) {
            int idx = it * 64 + lane;
            int row = idx >> 7;          // 0..15
            int j = idx & 127;           // float4 index within 512-float row
            float wgt = wld[row * 8 + (j >> 4)];
            float4 vv = *(const float4*)&vld[row * 68 + (j & 15) * 4];
            f32x4 o;
            o[0] = wgt * vv.x; o[1] = wgt * vv.y; o[2] = wgt * vv.z; o[3] = wgt * vv.w;
            __builtin_nontemporal_store(o, &outp[(size_t)row * 128 + j]);
        }

        r0 = (r0 == 4) ? 0 : (r0 + 1);
        cur = nxt;
        nxt = aft;
        first = false;
    }
#undef TILE16
#undef CSTEP
}

extern "C" void kernel_launch(void* const* d_in, const int* in_sizes, int n_in,
                              void* d_out, int out_size, void* d_ws, size_t ws_size,
                              hipStream_t stream) {
    const float* x  = (const float*)d_in[0];
    const float* Wk = (const float*)d_in[1];
    const float* bk = (const float*)d_in[2];
    const float* Wq = (const float*)d_in[3];
    const float* bq = (const float*)d_in[4];
    const float* Wv = (const float*)d_in[5];
    const float* bv = (const float*)d_in[6];
    float* out = (float*)d_out;

    unsigned short* Bp = (unsigned short*)d_ws;          // 81920 B
    float* qb = (float*)((char*)d_ws + 81920);           // 8 floats
    u32* ctr = (u32*)((char*)d_ws + 81984);              // tile counter

    qg_prepack<<<20, 256, 0, stream>>>(Wk, bk, Wq, bq, Wv, Bp, qb, ctr);
    qg_main<<<256, 256, 0, stream>>>(x, bv, Bp, qb, ctr, out);
}

// Round 14
// 101.818 us; speedup vs baseline: 1.4797x; 1.4797x over previous
//
#include <hip/hip_runtime.h>

#define NROWS 100000
#define IN_DIM 512

typedef __attribute__((ext_vector_type(8))) short short8;
typedef __attribute__((ext_vector_type(4))) float f32x4;

__device__ inline unsigned short f2bf(float f) {
    union { float f; unsigned u; } v; v.f = f;
    unsigned u = v.u;
    return (unsigned short)((u + 0x7FFFu + ((u >> 16) & 1u)) >> 16);
}

// Prepack: B-fragments (bf16) in exact MFMA lane order + fused que bias.
// B = [80 cols x 512 k]: cols 0..63 = Wv, 64..71 = Wq@Wk, 72..79 = 0.
// Bp layout: [t(5)][ks(16)][lane(64)][e(8)] bf16.
__global__ void qg_prepack(const float* __restrict__ Wk, const float* __restrict__ bk,
                           const float* __restrict__ Wq, const float* __restrict__ bq,
                           const float* __restrict__ Wv,
                           unsigned short* __restrict__ Bp, float* __restrict__ qb) {
    int id = blockIdx.x * 256 + threadIdx.x;  // 0..5119
    if (id < 8) {
        float s = bq[id];
        #pragma unroll 4
        for (int j = 0; j < 100; ++j) s += Wq[id * 100 + j] * bk[j];
        qb[id] = s;
    }
    if (id >= 5120) return;
    int lane = id & 63;
    int ks = (id >> 6) & 15;
    int t = id >> 10;
    int c = t * 16 + (lane & 15);
    int kk = ks * 32 + (lane >> 4) * 8;
    short8 pk;
    #pragma unroll
    for (int e = 0; e < 8; ++e) {
        int k2 = kk + e;
        float w;
        if (c < 64) {
            w = Wv[c * IN_DIM + k2];
        } else if (c < 72) {
            float s = 0.f;
            #pragma unroll 4
            for (int j = 0; j < 100; ++j) s += Wq[(c - 64) * 100 + j] * Wk[j * IN_DIM + k2];
            w = s;
        } else {
            w = 0.f;
        }
        pk[e] = (short)f2bf(w);
    }
    ((short8*)Bp)[id] = pk;
}

// Register map (hardcoded, reserved via clobbers):
//   A slot0 v48-55, slot1 v56-63, slot2 v64-71  (8 f32 each)
//   B slot0 v72-91, slot1 v92-111, slot2 v112-131 (5 x dwordx4 each)
//   offsets v132 (A), v133-137 (B t=0..4)
//   acc v140-159 (5 x f32x4, 4-aligned)
#define CA0 "v48","v49","v50","v51","v52","v53","v54","v55"
#define CA1 "v56","v57","v58","v59","v60","v61","v62","v63"
#define CA2 "v64","v65","v66","v67","v68","v69","v70","v71"
#define CB0 "v72","v73","v74","v75","v76","v77","v78","v79","v80","v81","v82","v83","v84","v85","v86","v87","v88","v89","v90","v91"
#define CB1 "v92","v93","v94","v95","v96","v97","v98","v99","v100","v101","v102","v103","v104","v105","v106","v107","v108","v109","v110","v111"
#define CB2 "v112","v113","v114","v115","v116","v117","v118","v119","v120","v121","v122","v123","v124","v125","v126","v127","v128","v129","v130","v131"
#define COFF "v132","v133","v134","v135","v136","v137"
#define CACC "v140","v141","v142","v143","v144","v145","v146","v147","v148","v149","v150","v151","v152","v153","v154","v155","v156","v157","v158","v159"

// Issue one batch (2 A + 5 B loads) into a slot; offsets self-advance.
#define ISSUE(AR0, AR1, B0, B1, B2, B3, B4, CLA, CLB)                          \
    asm volatile(                                                              \
        "global_load_dwordx4 " AR0 ", v132, %0 offset:0\n\t"                   \
        "global_load_dwordx4 " AR1 ", v132, %0 offset:16\n\t"                  \
        "v_add_u32 v132, 0x80, v132\n\t"                                       \
        "global_load_dwordx4 " B0 ", v133, %1 offset:0\n\t"                    \
        "v_add_u32 v133, 0x400, v133\n\t"                                      \
        "global_load_dwordx4 " B1 ", v134, %1 offset:0\n\t"                    \
        "v_add_u32 v134, 0x400, v134\n\t"                                      \
        "global_load_dwordx4 " B2 ", v135, %1 offset:0\n\t"                    \
        "v_add_u32 v135, 0x400, v135\n\t"                                      \
        "global_load_dwordx4 " B3 ", v136, %1 offset:0\n\t"                    \
        "v_add_u32 v136, 0x400, v136\n\t"                                      \
        "global_load_dwordx4 " B4 ", v137, %1 offset:0\n\t"                    \
        "v_add_u32 v137, 0x400, v137"                                          \
        :: "s"(x), "s"(Bp) : "memory", CLA, CLB, COFF)

#define ISSUE0 ISSUE("v[48:51]", "v[52:55]", "v[72:75]", "v[76:79]", "v[80:83]", "v[84:87]", "v[88:91]", CA0, CB0)
#define ISSUE1 ISSUE("v[56:59]", "v[60:63]", "v[92:95]", "v[96:99]", "v[100:103]", "v[104:107]", "v[108:111]", CA1, CB1)
#define ISSUE2 ISSUE("v[64:67]", "v[68:71]", "v[112:115]", "v[116:119]", "v[120:123]", "v[124:127]", "v[128:131]", CA2, CB2)

// Consume one slot: wait ladder, pack f32->bf16 in place, 5 MFMAs.
#define CONS(NW, A0s, A1s, A2s, A3s, AF, B0, B1, B2, B3, B4, CLA)              \
    asm volatile("s_waitcnt vmcnt(" NW ")" ::: "memory");                      \
    asm volatile(                                                              \
        "v_cvt_pk_bf16_f32 " A0s "\n\t"                                        \
        "v_cvt_pk_bf16_f32 " A1s "\n\t"                                        \
        "v_cvt_pk_bf16_f32 " A2s "\n\t"                                        \
        "v_cvt_pk_bf16_f32 " A3s "\n\t"                                        \
        "s_nop 1\n\t"                                                          \
        "v_mfma_f32_16x16x32_bf16 v[140:143], " AF ", " B0 ", v[140:143]\n\t"  \
        "v_mfma_f32_16x16x32_bf16 v[144:147], " AF ", " B1 ", v[144:147]\n\t"  \
        "v_mfma_f32_16x16x32_bf16 v[148:151], " AF ", " B2 ", v[148:151]\n\t"  \
        "v_mfma_f32_16x16x32_bf16 v[152:155], " AF ", " B3 ", v[152:155]\n\t"  \
        "v_mfma_f32_16x16x32_bf16 v[156:159], " AF ", " B4 ", v[156:159]"      \
        ::: "memory", CLA, CACC)

#define CONS0(NW) CONS(NW, "v48, v48, v49", "v49, v50, v51", "v50, v52, v53", "v51, v54, v55", \
                       "v[48:51]", "v[72:75]", "v[76:79]", "v[80:83]", "v[84:87]", "v[88:91]", CA0)
#define CONS1(NW) CONS(NW, "v56, v56, v57", "v57, v58, v59", "v58, v60, v61", "v59, v62, v63", \
                       "v[56:59]", "v[92:95]", "v[96:99]", "v[100:103]", "v[104:107]", "v[108:111]", CA1)
#define CONS2(NW) CONS(NW, "v64, v64, v65", "v65, v66, v67", "v66, v68, v69", "v67, v70, v71", \
                       "v[64:67]", "v[112:115]", "v[116:119]", "v[120:123]", "v[124:127]", "v[128:131]", CA2)

// Main: 128 threads = 2 independent waves, 16 rows/wave, grid 3125 (exact).
// K-loop entirely in inline asm with hardcoded physical VGPRs: 3-batch ring,
// 21 outstanding 1KB loads/wave GUARANTEED (regalloc cannot interfere).
__global__ __launch_bounds__(128, 2) void qg_main(const float* __restrict__ x,
                                                  const float* __restrict__ bv,
                                                  const unsigned short* __restrict__ Bp,
                                                  const float* __restrict__ qb,
                                                  float* __restrict__ out) {
    __shared__ float vlds[2][16][68];
    __shared__ float wlds[2][16][8];
    const int tid = threadIdx.x;
    const int w = tid >> 6;
    const int lane = tid & 63;
    const int g = lane >> 4;       // k sub-block
    const int cl = lane & 15;      // A row within tile / B col within tile
    const int rowbase = (blockIdx.x * 2 + w) * 16;   // 3125*32 = 100000 exact

    const unsigned voffA = (unsigned)((rowbase + cl) * 512 + g * 8) * 4u;
    const unsigned voffB = (unsigned)lane * 16u;

    // Bias preload, drained before the hand-counted FIFO region.
    float bvr[4];
    #pragma unroll
    for (int t = 0; t < 4; ++t) bvr[t] = bv[t * 16 + cl];
    float qbr = qb[cl & 7];
    asm volatile("s_waitcnt vmcnt(0)" ::: "memory");

    // Init offset regs + zero accumulators.
    asm volatile(
        "v_mov_b32 v132, %0\n\t"
        "v_mov_b32 v133, %1\n\t"
        "v_mov_b32 v134, %2\n\t"
        "v_mov_b32 v135, %3\n\t"
        "v_mov_b32 v136, %4\n\t"
        "v_mov_b32 v137, %5"
        :: "v"(voffA), "v"(voffB), "v"(voffB + 16384u), "v"(voffB + 32768u),
           "v"(voffB + 49152u), "v"(voffB + 65536u)
        : COFF);
    asm volatile(
        "v_mov_b32 v140, 0\n\tv_mov_b32 v141, 0\n\tv_mov_b32 v142, 0\n\tv_mov_b32 v143, 0\n\t"
        "v_mov_b32 v144, 0\n\tv_mov_b32 v145, 0\n\tv_mov_b32 v146, 0\n\tv_mov_b32 v147, 0\n\t"
        "v_mov_b32 v148, 0\n\tv_mov_b32 v149, 0\n\tv_mov_b32 v150, 0\n\tv_mov_b32 v151, 0\n\t"
        "v_mov_b32 v152, 0\n\tv_mov_b32 v153, 0\n\tv_mov_b32 v154, 0\n\tv_mov_b32 v155, 0\n\t"
        "v_mov_b32 v156, 0\n\tv_mov_b32 v157, 0\n\tv_mov_b32 v158, 0\n\tv_mov_b32 v159, 0"
        ::: CACC);

    // Prologue: 3 batches (21 loads) in flight.
    ISSUE0; ISSUE1; ISSUE2;
    // Steady state: consume S (vmcnt(14): 2 newer batches may remain), issue S+3.
    CONS0("14"); ISSUE0;   // S=0
    CONS1("14"); ISSUE1;   // S=1
    CONS2("14"); ISSUE2;   // S=2
    CONS0("14"); ISSUE0;   // S=3
    CONS1("14"); ISSUE1;   // S=4
    CONS2("14"); ISSUE2;   // S=5
    CONS0("14"); ISSUE0;   // S=6
    CONS1("14"); ISSUE1;   // S=7
    CONS2("14"); ISSUE2;   // S=8
    CONS0("14"); ISSUE0;   // S=9
    CONS1("14"); ISSUE1;   // S=10
    CONS2("14"); ISSUE2;   // S=11
    CONS0("14"); ISSUE0;   // S=12
    CONS1("14");           // S=13
    CONS2("7");            // S=14
    CONS0("0");            // S=15

    // MFMA -> VALU-read hazard padding, then extract accumulators.
    asm volatile("s_nop 7\n\ts_nop 7\n\ts_nop 7");
    float ac[5][4];
    asm volatile("v_mov_b32 %0, v140" : "=v"(ac[0][0]));
    asm volatile("v_mov_b32 %0, v141" : "=v"(ac[0][1]));
    asm volatile("v_mov_b32 %0, v142" : "=v"(ac[0][2]));
    asm volatile("v_mov_b32 %0, v143" : "=v"(ac[0][3]));
    asm volatile("v_mov_b32 %0, v144" : "=v"(ac[1][0]));
    asm volatile("v_mov_b32 %0, v145" : "=v"(ac[1][1]));
    asm volatile("v_mov_b32 %0, v146" : "=v"(ac[1][2]));
    asm volatile("v_mov_b32 %0, v147" : "=v"(ac[1][3]));
    asm volatile("v_mov_b32 %0, v148" : "=v"(ac[2][0]));
    asm volatile("v_mov_b32 %0, v149" : "=v"(ac[2][1]));
    asm volatile("v_mov_b32 %0, v150" : "=v"(ac[2][2]));
    asm volatile("v_mov_b32 %0, v151" : "=v"(ac[2][3]));
    asm volatile("v_mov_b32 %0, v152" : "=v"(ac[3][0]));
    asm volatile("v_mov_b32 %0, v153" : "=v"(ac[3][1]));
    asm volatile("v_mov_b32 %0, v154" : "=v"(ac[3][2]));
    asm volatile("v_mov_b32 %0, v155" : "=v"(ac[3][3]));
    asm volatile("v_mov_b32 %0, v156" : "=v"(ac[4][0]));
    asm volatile("v_mov_b32 %0, v157" : "=v"(ac[4][1]));
    asm volatile("v_mov_b32 %0, v158" : "=v"(ac[4][2]));
    asm volatile("v_mov_b32 %0, v159" : "=v"(ac[4][3]));

    // ---- Per-wave epilogue (intra-wave lockstep; lgkmcnt ordering only) ----
    // C layout: col = lane&15, row = (lane>>4)*4 + reg  (verified m89).
    #pragma unroll
    for (int t = 0; t < 4; ++t) {
        #pragma unroll
        for (int r = 0; r < 4; ++r)
            vlds[w][g * 4 + r][t * 16 + cl] = ac[t][r] + bvr[t];
    }
    if (cl < 8) {
        #pragma unroll
        for (int r = 0; r < 4; ++r)
            wlds[w][g * 4 + r][cl] = ac[4][r] + qbr;
    }
    asm volatile("s_waitcnt lgkmcnt(0)" ::: "memory");

    // Softmax over the 8 que values: lanes 0..15 each own one row.
    if (lane < 16) {
        float q[8];
        float m = -1e30f;
        #pragma unroll
        for (int k = 0; k < 8; ++k) { q[k] = wlds[w][lane][k]; m = fmaxf(m, q[k]); }
        float ssum = 0.f;
        #pragma unroll
        for (int k = 0; k < 8; ++k) { q[k] = __expf(q[k] - m); ssum += q[k]; }
        float inv = 1.f / ssum;
        #pragma unroll
        for (int k = 0; k < 8; ++k) wlds[w][lane][k] = q[k] * inv;
    }
    asm volatile("s_waitcnt lgkmcnt(0)" ::: "memory");

    // Coalesced NONTEMPORAL output: out[row][k][v] = w[k] * val[v]; 1 KB/instr.
    f32x4* outp = (f32x4*)out + (size_t)rowbase * 128;
    #pragma unroll
    for (int it = 0; it < 32; ++it) {
        int idx = it * 64 + lane;
        int row = idx >> 7;             // 0..15
        int j = idx & 127;              // float4 index within 512-float out row
        float wgt = wlds[w][row][j >> 4];
        float4 vv = *(const float4*)&vlds[w][row][(j & 15) * 4];
        f32x4 o;
        o[0] = wgt * vv.x; o[1] = wgt * vv.y; o[2] = wgt * vv.z; o[3] = wgt * vv.w;
        __builtin_nontemporal_store(o, &outp[(size_t)row * 128 + j]);
    }
}

extern "C" void kernel_launch(void* const* d_in, const int* in_sizes, int n_in,
                              void* d_out, int out_size, void* d_ws, size_t ws_size,
                              hipStream_t stream) {
    const float* x  = (const float*)d_in[0];
    const float* Wk = (const float*)d_in[1];
    const float* bk = (const float*)d_in[2];
    const float* Wq = (const float*)d_in[3];
    const float* bq = (const float*)d_in[4];
    const float* Wv = (const float*)d_in[5];
    const float* bv = (const float*)d_in[6];
    float* out = (float*)d_out;

    unsigned short* Bp = (unsigned short*)d_ws;          // 81920 B
    float* qb = (float*)((char*)d_ws + 81920);           // 8 floats

    qg_prepack<<<20, 256, 0, stream>>>(Wk, bk, Wq, bq, Wv, Bp, qb);
    qg_main<<<3125, 128, 0, stream>>>(x, bv, Bp, qb, out);
}